// Round 4
// baseline (1008.091 us; speedup 1.0000x reference)
//
#include <hip/hip_runtime.h>
#include <math.h>

#define NN 50000
#define NEDGE 512000
#define DD 128

typedef short bf16x8 __attribute__((ext_vector_type(8)));
typedef float f32x4 __attribute__((ext_vector_type(4)));

__device__ __forceinline__ short f2bf(float f){
  union { float f; unsigned u; } v; v.f = f;
  unsigned u = v.u;
  return (short)((u + 0x7fffu + ((u >> 16) & 1u)) >> 16);
}
__device__ __forceinline__ float bf2f(short s){
  union { unsigned u; float f; } v; v.u = ((unsigned)(unsigned short)s) << 16; return v.f;
}

__device__ __forceinline__ bf16x8 packA(const float* __restrict__ rowp, int kbase){
  float4 x = *(const float4*)(rowp + kbase);
  float4 y = *(const float4*)(rowp + kbase + 4);
  bf16x8 r;
  r[0]=f2bf(x.x); r[1]=f2bf(x.y); r[2]=f2bf(x.z); r[3]=f2bf(x.w);
  r[4]=f2bf(y.x); r[5]=f2bf(y.y); r[6]=f2bf(y.z); r[7]=f2bf(y.w);
  return r;
}

// ---------------- weight prep: fp32 W[K][N] -> bf16 WT[N][K] ----------------
__global__ __launch_bounds__(256) void prep_w(
    const float* __restrict__ Wq, const float* __restrict__ Wk,
    const float* __restrict__ Wv, const float* __restrict__ We,
    const float* __restrict__ Wo, const float* __restrict__ W1,
    const float* __restrict__ W2, short* __restrict__ wdst){
  int id = blockIdx.x*256 + threadIdx.x;
  const float* src; short* dst; int K, NCOL, local;
  if (id < 81920){
    int m = id >> 14; local = id & 16383; K = 128; NCOL = 128;
    src = (m==0)?Wq:(m==1)?Wk:(m==2)?Wv:(m==3)?We:Wo;
    dst = wdst + m*16384;
  } else if (id < 114688){
    local = id - 81920; K = 128; NCOL = 256; src = W1; dst = wdst + 81920;
  } else if (id < 147456){
    local = id - 114688; K = 256; NCOL = 128; src = W2; dst = wdst + 114688;
  } else return;
  int k = local / NCOL, n = local % NCOL;
  dst[n*K + k] = f2bf(src[local]);
}

// ---------------- QKV: Q/K/V = h @ Wq/Wk/Wv, stored bf16 ----------------
__global__ __launch_bounds__(256) void qkv_gemm(
    const float* __restrict__ h, const short* __restrict__ wT,
    short* __restrict__ Qb, short* __restrict__ Kb, short* __restrict__ Vb){
  const short* WqT = wT;
  const short* WkT = wT + 16384;
  const short* WvT = wT + 32768;
  int lane = threadIdx.x & 63, wave = threadIdx.x >> 6;
  int r16 = lane & 15, kg = lane >> 4;
  int rowbase = blockIdx.x*64 + wave*16;
  int arow = rowbase + r16; if (arow > NN-1) arow = NN-1;
  const float* Arow = h + (size_t)arow*DD;
  f32x4 acc[3][8];
  #pragma unroll
  for (int m=0;m<3;m++)
    #pragma unroll
    for (int j=0;j<8;j++) acc[m][j] = (f32x4){0.f,0.f,0.f,0.f};
  #pragma unroll
  for (int kc=0;kc<4;kc++){
    int kb = kc*32 + kg*8;
    bf16x8 a = packA(Arow, kb);
    #pragma unroll
    for (int j=0;j<8;j++){
      bf16x8 bq = *(const bf16x8*)(WqT + (j*16+r16)*DD + kb);
      acc[0][j] = __builtin_amdgcn_mfma_f32_16x16x32_bf16(a, bq, acc[0][j], 0,0,0);
      bf16x8 bk = *(const bf16x8*)(WkT + (j*16+r16)*DD + kb);
      acc[1][j] = __builtin_amdgcn_mfma_f32_16x16x32_bf16(a, bk, acc[1][j], 0,0,0);
      bf16x8 bv = *(const bf16x8*)(WvT + (j*16+r16)*DD + kb);
      acc[2][j] = __builtin_amdgcn_mfma_f32_16x16x32_bf16(a, bv, acc[2][j], 0,0,0);
    }
  }
  int orow0 = rowbase + kg*4;
  #pragma unroll
  for (int j=0;j<8;j++){
    #pragma unroll
    for (int r=0;r<4;r++){
      int row = orow0 + r;
      if (row < NN){
        size_t idx = (size_t)row*DD + j*16 + r16;
        Qb[idx] = f2bf(acc[0][j][r]);
        Kb[idx] = f2bf(acc[1][j][r]);
        Vb[idx] = f2bf(acc[2][j][r]);
      }
    }
  }
}

// ---------------- CSR build ----------------
__global__ __launch_bounds__(256) void hist_dst(
    const int* __restrict__ dst, int* __restrict__ counts){
  int id = blockIdx.x*256 + threadIdx.x;
  if (id < NEDGE) atomicAdd(&counts[dst[id]], 1);
}

__global__ __launch_bounds__(256) void scan_counts(
    const int* __restrict__ counts, int* __restrict__ off){
  __shared__ int ps[256];
  int t = threadIdx.x;
  int base = t*196;
  int sum = 0;
  for (int i=0;i<196;i++){ int idx=base+i; if (idx<NN) sum += counts[idx]; }
  ps[t] = sum; __syncthreads();
  for (int o=1;o<256;o<<=1){
    int v2 = (t>=o) ? ps[t-o] : 0;
    __syncthreads();
    ps[t] += v2;
    __syncthreads();
  }
  int run = ps[t] - sum;   // exclusive prefix of this chunk
  for (int i=0;i<196;i++){
    int idx = base+i;
    if (idx < NN){ off[idx] = run; run += counts[idx]; }
  }
  if (t == 255) off[NN] = run;
}

__global__ __launch_bounds__(256) void scatter_perm(
    const int* __restrict__ dst, const int* __restrict__ off,
    int* __restrict__ cursor, int* __restrict__ perm){
  int id = blockIdx.x*256 + threadIdx.x;
  if (id < NEDGE){
    int d = dst[id];
    int r = atomicAdd(&cursor[d], 1);
    perm[off[d] + r] = id;
  }
}

// -------- edge pass 1: Eh = e@We (LDS only), scores -> sArr,
//          BN partial stats of (e+Eh). NO e2 write (recomputed in pass 2). ----
__global__ __launch_bounds__(256) void edge_fused(
    const float* __restrict__ e, const short* __restrict__ WeT,
    const short* __restrict__ Qb, const short* __restrict__ Kb,
    const int* __restrict__ src, const int* __restrict__ dst,
    float* __restrict__ sArr, float* __restrict__ part){
  __shared__ short EhL[64*128];   // 16KB bf16, head-group XOR-swizzled by edge
  __shared__ float csum[DD], csq[DD];
  __shared__ int srcL[64], dstL[64];
  int tid = threadIdx.x;
  int rowbase = blockIdx.x*64;
  if (tid < DD){ csum[tid] = 0.f; csq[tid] = 0.f; }
  if (tid < 64){ srcL[tid] = src[rowbase+tid]; dstL[tid] = dst[rowbase+tid]; }
  __syncthreads();
  int lane = tid & 63, wave = tid >> 6;
  int r16 = lane & 15, kg = lane >> 4;
  int ebase = rowbase + wave*16;
  const float* Arow = e + (size_t)(ebase + r16)*DD;
  f32x4 acc[8];
  #pragma unroll
  for (int j=0;j<8;j++) acc[j] = (f32x4){0.f,0.f,0.f,0.f};
  #pragma unroll
  for (int kc=0;kc<4;kc++){
    int kb = kc*32 + kg*8;
    bf16x8 a = packA(Arow, kb);
    #pragma unroll
    for (int j=0;j<8;j++){
      bf16x8 b = *(const bf16x8*)(WeT + (j*16+r16)*DD + kb);
      acc[j] = __builtin_amdgcn_mfma_f32_16x16x32_bf16(a, b, acc[j], 0,0,0);
    }
  }
  // ---- phase 1: Eh->LDS (bf16), register BN stats of e+Eh ----
  float ssum[8], ssq[8];
  #pragma unroll
  for (int j=0;j<8;j++){ ssum[j]=0.f; ssq[j]=0.f; }
  #pragma unroll
  for (int r=0;r<4;r++){
    int le = wave*16 + kg*4 + r;
    int ed = rowbase + le;
    int sw = le & 7;
    const float* erow = e + (size_t)ed*DD;
    #pragma unroll
    for (int j=0;j<8;j++){
      float ehv = acc[j][r];
      EhL[le*128 + ((j^sw)*16) + r16] = f2bf(ehv);
      float v = erow[j*16+r16] + ehv;
      ssum[j] += v; ssq[j] += v*v;
    }
  }
  #pragma unroll
  for (int j=0;j<8;j++){
    ssum[j] += __shfl_xor(ssum[j],16); ssum[j] += __shfl_xor(ssum[j],32);
    ssq[j]  += __shfl_xor(ssq[j],16);  ssq[j]  += __shfl_xor(ssq[j],32);
  }
  if (kg == 0){
    #pragma unroll
    for (int j=0;j<8;j++){
      atomicAdd(&csum[j*16+r16], ssum[j]);
      atomicAdd(&csq[j*16+r16],  ssq[j]);
    }
  }
  __syncthreads();
  // ---- phase 2: one lane per (edge,head): score -> sArr (coalesced) ----
  #pragma unroll
  for (int it=0; it<2; ++it){
    int le = it*32 + (tid >> 3);
    int hd = tid & 7;
    int sj = srcL[le], dj = dstL[le];
    const short* kp = Kb + (size_t)sj*DD + hd*16;
    const short* qp = Qb + (size_t)dj*DD + hd*16;
    bf16x8 k0 = *(const bf16x8*)kp;
    bf16x8 k1 = *(const bf16x8*)(kp+8);
    bf16x8 q0 = *(const bf16x8*)qp;
    bf16x8 q1 = *(const bf16x8*)(qp+8);
    const short* ehp = &EhL[le*128 + ((hd^(le&7))*16)];
    bf16x8 e0 = *(const bf16x8*)ehp;
    bf16x8 e1 = *(const bf16x8*)(ehp+8);
    float p = 0.f;
    #pragma unroll
    for (int i=0;i<8;i++) p += bf2f(k0[i])*bf2f(q0[i])*bf2f(e0[i]);
    #pragma unroll
    for (int i=0;i<8;i++) p += bf2f(k1[i])*bf2f(q1[i])*bf2f(e1[i]);
    p *= 0.25f;
    sArr[(size_t)(rowbase+le)*8 + hd] = __expf(fminf(fmaxf(p,-5.f),5.f));
  }
  if (tid < DD){
    part[(size_t)blockIdx.x*256 + tid]      = csum[tid];
    part[(size_t)blockIdx.x*256 + DD + tid] = csq[tid];
  }
}

// -------- edge pass 2: recompute Eh, write e2 = BN(e+Eh) fp32 to d_out --------
__global__ __launch_bounds__(256) void edge_apply(
    const float* __restrict__ e, const short* __restrict__ WeT,
    const float* __restrict__ ssE, float* __restrict__ e2){
  int lane = threadIdx.x & 63, wave = threadIdx.x >> 6;
  int r16 = lane & 15, kg = lane >> 4;
  int ebase = blockIdx.x*64 + wave*16;
  const float* Arow = e + (size_t)(ebase + r16)*DD;
  f32x4 acc[8];
  #pragma unroll
  for (int j=0;j<8;j++) acc[j] = (f32x4){0.f,0.f,0.f,0.f};
  #pragma unroll
  for (int kc=0;kc<4;kc++){
    int kb = kc*32 + kg*8;
    bf16x8 a = packA(Arow, kb);
    #pragma unroll
    for (int j=0;j<8;j++){
      bf16x8 b = *(const bf16x8*)(WeT + (j*16+r16)*DD + kb);
      acc[j] = __builtin_amdgcn_mfma_f32_16x16x32_bf16(a, b, acc[j], 0,0,0);
    }
  }
  float sc[8], sh[8];
  #pragma unroll
  for (int j=0;j<8;j++){ sc[j]=ssE[j*16+r16]; sh[j]=ssE[DD+j*16+r16]; }
  #pragma unroll
  for (int r=0;r<4;r++){
    int ed = ebase + kg*4 + r;
    const float* erow = e + (size_t)ed*DD;
    float* orow = e2 + (size_t)ed*DD;
    #pragma unroll
    for (int j=0;j<8;j++){
      float v = erow[j*16+r16] + acc[j][r];
      orow[j*16+r16] = v*sc[j] + sh[j];
    }
  }
}

// ---------------- node aggregation: one wave per dst node, no atomics ----------------
__global__ __launch_bounds__(256) void node_agg(
    const int* __restrict__ off, const int* __restrict__ perm,
    const int* __restrict__ src, const float* __restrict__ sArr,
    const short* __restrict__ Vb, short* __restrict__ hA){
  int wave = threadIdx.x >> 6, lane = threadIdx.x & 63;
  int node = blockIdx.x*4 + wave;
  if (node >= NN) return;
  int beg = off[node], end = off[node+1];
  int col2 = lane*2;
  int hd = lane >> 3;
  float w0 = 0.f, w1 = 0.f, zh = 0.f;
  for (int ed = beg; ed < end; ++ed){
    int pe = perm[ed];
    int sj = src[pe];
    float s = sArr[(size_t)pe*8 + hd];
    unsigned vv = *(const unsigned*)(Vb + (size_t)sj*DD + col2);
    w0 += bf2f((short)(vv & 0xffff)) * s;
    w1 += bf2f((short)(vv >> 16)) * s;
    zh += s;
  }
  float inv = 1.f/(zh + 1e-6f);
  unsigned outv = (((unsigned)(unsigned short)f2bf(w1*inv)) << 16)
                |  ((unsigned)(unsigned short)f2bf(w0*inv));
  *(unsigned*)(hA + (size_t)node*DD + col2) = outv;
}

// ---------------- h2pre(bf16) = hA @ Wo + bo + h, BN partials ----------------
__global__ __launch_bounds__(256) void attn_out(
    const short* __restrict__ hA,
    const short* __restrict__ WoT, const float* __restrict__ bo,
    const float* __restrict__ h, short* __restrict__ h2pre,
    float* __restrict__ part){
  __shared__ float csum[DD], csq[DD];
  if (threadIdx.x < DD){ csum[threadIdx.x] = 0.f; csq[threadIdx.x] = 0.f; }
  __syncthreads();
  int lane = threadIdx.x & 63, wave = threadIdx.x >> 6;
  int r16 = lane & 15, kg = lane >> 4;
  int rowbase = blockIdx.x*64 + wave*16;
  int arow = rowbase + r16; if (arow > NN-1) arow = NN-1;
  const short* Arow = hA + (size_t)arow*DD;
  f32x4 acc[8];
  #pragma unroll
  for (int j=0;j<8;j++) acc[j] = (f32x4){0.f,0.f,0.f,0.f};
  #pragma unroll
  for (int kc=0;kc<4;kc++){
    int kb = kc*32 + kg*8;
    bf16x8 a = *(const bf16x8*)(Arow + kb);
    #pragma unroll
    for (int j=0;j<8;j++){
      bf16x8 b = *(const bf16x8*)(WoT + (j*16+r16)*DD + kb);
      acc[j] = __builtin_amdgcn_mfma_f32_16x16x32_bf16(a, b, acc[j], 0,0,0);
    }
  }
  int orow0 = rowbase + kg*4;
  #pragma unroll
  for (int j=0;j<8;j++){
    #pragma unroll
    for (int r=0;r<4;r++){
      int row = orow0 + r;
      if (row < NN){
        int col = j*16 + r16;
        float v = acc[j][r] + bo[col] + h[(size_t)row*DD + col];
        h2pre[(size_t)row*DD + col] = f2bf(v);
        atomicAdd(&csum[col], v);
        atomicAdd(&csq[col], v*v);
      }
    }
  }
  __syncthreads();
  if (threadIdx.x < DD){
    part[(size_t)blockIdx.x*256 + threadIdx.x]      = csum[threadIdx.x];
    part[(size_t)blockIdx.x*256 + DD + threadIdx.x] = csq[threadIdx.x];
  }
}

// ---------------- FFN1: relu(BN1(h2pre) @ W1 + b1) -> bf16 ----------------
__global__ __launch_bounds__(256) void ffn1_gemm(
    const short* __restrict__ h2pre, const float* __restrict__ ss1,
    const short* __restrict__ W1T, const float* __restrict__ b1,
    short* __restrict__ ffn1){
  int lane = threadIdx.x & 63, wave = threadIdx.x >> 6;
  int r16 = lane & 15, kg = lane >> 4;
  int rowbase = blockIdx.x*64 + wave*16;
  int arow = rowbase + r16; if (arow > NN-1) arow = NN-1;
  const short* Arow = h2pre + (size_t)arow*DD;
  f32x4 acc[16];
  #pragma unroll
  for (int j=0;j<16;j++) acc[j] = (f32x4){0.f,0.f,0.f,0.f};
  #pragma unroll
  for (int kc=0;kc<4;kc++){
    int kb = kc*32 + kg*8;
    bf16x8 raw = *(const bf16x8*)(Arow + kb);
    float4 s0 = *(const float4*)(ss1 + kb);
    float4 s1 = *(const float4*)(ss1 + kb + 4);
    float4 t0 = *(const float4*)(ss1 + DD + kb);
    float4 t1 = *(const float4*)(ss1 + DD + kb + 4);
    bf16x8 a;
    a[0]=f2bf(bf2f(raw[0])*s0.x+t0.x); a[1]=f2bf(bf2f(raw[1])*s0.y+t0.y);
    a[2]=f2bf(bf2f(raw[2])*s0.z+t0.z); a[3]=f2bf(bf2f(raw[3])*s0.w+t0.w);
    a[4]=f2bf(bf2f(raw[4])*s1.x+t1.x); a[5]=f2bf(bf2f(raw[5])*s1.y+t1.y);
    a[6]=f2bf(bf2f(raw[6])*s1.z+t1.z); a[7]=f2bf(bf2f(raw[7])*s1.w+t1.w);
    #pragma unroll
    for (int j=0;j<16;j++){
      bf16x8 b = *(const bf16x8*)(W1T + (j*16+r16)*DD + kb);
      acc[j] = __builtin_amdgcn_mfma_f32_16x16x32_bf16(a, b, acc[j], 0,0,0);
    }
  }
  int orow0 = rowbase + kg*4;
  #pragma unroll
  for (int j=0;j<16;j++){
    #pragma unroll
    for (int r=0;r<4;r++){
      int row = orow0 + r;
      if (row < NN){
        int col = j*16 + r16;
        float v = fmaxf(acc[j][r] + b1[col], 0.f);
        ffn1[(size_t)row*256 + col] = f2bf(v);
      }
    }
  }
}

// ---------------- FFN2: h3pre = BN1(h2pre) + ffn1 @ W2 + b2, BN partials ----------------
__global__ __launch_bounds__(256) void ffn2_gemm(
    const short* __restrict__ ffn1, const short* __restrict__ W2T,
    const float* __restrict__ b2, const short* __restrict__ h2pre,
    const float* __restrict__ ss1, float* __restrict__ h3pre,
    float* __restrict__ part){
  __shared__ float csum[DD], csq[DD];
  if (threadIdx.x < DD){ csum[threadIdx.x] = 0.f; csq[threadIdx.x] = 0.f; }
  __syncthreads();
  int lane = threadIdx.x & 63, wave = threadIdx.x >> 6;
  int r16 = lane & 15, kg = lane >> 4;
  int rowbase = blockIdx.x*64 + wave*16;
  int arow = rowbase + r16; if (arow > NN-1) arow = NN-1;
  const short* Arow = ffn1 + (size_t)arow*256;
  f32x4 acc[8];
  #pragma unroll
  for (int j=0;j<8;j++) acc[j] = (f32x4){0.f,0.f,0.f,0.f};
  #pragma unroll
  for (int kc=0;kc<8;kc++){
    int kb = kc*32 + kg*8;
    bf16x8 a = *(const bf16x8*)(Arow + kb);
    #pragma unroll
    for (int j=0;j<8;j++){
      bf16x8 b = *(const bf16x8*)(W2T + (j*16+r16)*256 + kb);
      acc[j] = __builtin_amdgcn_mfma_f32_16x16x32_bf16(a, b, acc[j], 0,0,0);
    }
  }
  int orow0 = rowbase + kg*4;
  #pragma unroll
  for (int j=0;j<8;j++){
    #pragma unroll
    for (int r=0;r<4;r++){
      int row = orow0 + r;
      if (row < NN){
        int col = j*16 + r16;
        float x = bf2f(h2pre[(size_t)row*DD + col]);
        float h2bn = x*ss1[col] + ss1[DD+col];
        float v = h2bn + acc[j][r] + b2[col];
        h3pre[(size_t)row*DD + col] = v;
        atomicAdd(&csum[col], v);
        atomicAdd(&csq[col], v*v);
      }
    }
  }
  __syncthreads();
  if (threadIdx.x < DD){
    part[(size_t)blockIdx.x*256 + threadIdx.x]      = csum[threadIdx.x];
    part[(size_t)blockIdx.x*256 + DD + threadIdx.x] = csq[threadIdx.x];
  }
}

// ---------------- BN stats reduce: partials -> scale/shift ----------------
__global__ __launch_bounds__(256) void bn_reduce(
    const float* __restrict__ part, int nparts, float inv_n,
    const float* __restrict__ g, const float* __restrict__ b,
    float* __restrict__ ss){
  int col = blockIdx.x, t = threadIdx.x;
  float s = 0.f, q = 0.f;
  for (int i=t; i<nparts; i+=256){
    s += part[(size_t)i*256 + col];
    q += part[(size_t)i*256 + DD + col];
  }
  __shared__ float ls[256], lq[256];
  ls[t] = s; lq[t] = q; __syncthreads();
  for (int o2=128; o2>0; o2>>=1){
    if (t < o2){ ls[t] += ls[t+o2]; lq[t] += lq[t+o2]; }
    __syncthreads();
  }
  if (t == 0){
    float mean = ls[0]*inv_n;
    float var  = lq[0]*inv_n - mean*mean;
    float sc = g[col]*rsqrtf(var + 1e-5f);
    ss[col]      = sc;
    ss[DD + col] = b[col] - mean*sc;
  }
}

// ---------------- in-place BN apply (h3 only): x = x*scale + shift ----------------
__global__ __launch_bounds__(256) void bn_apply(
    float* __restrict__ x, size_t rows, const float* __restrict__ ss){
  size_t id = (size_t)blockIdx.x*256 + threadIdx.x;
  size_t total = rows*32;
  if (id >= total) return;
  float4* p = (float4*)x + id;
  int c = (int)(id & 31) * 4;
  float4 v = *p;
  v.x = v.x*ss[c]   + ss[DD+c];
  v.y = v.y*ss[c+1] + ss[DD+c+1];
  v.z = v.z*ss[c+2] + ss[DD+c+2];
  v.w = v.w*ss[c+3] + ss[DD+c+3];
  *p = v;
}

extern "C" void kernel_launch(void* const* d_in, const int* in_sizes, int n_in,
                              void* d_out, int out_size, void* d_ws, size_t ws_size,
                              hipStream_t stream){
  const float* h   = (const float*)d_in[0];
  const float* e   = (const float*)d_in[1];
  const int*   src = (const int*)d_in[2];
  const int*   dst = (const int*)d_in[3];
  const float* Wq  = (const float*)d_in[4];
  const float* Wk  = (const float*)d_in[5];
  const float* Wv  = (const float*)d_in[6];
  const float* We  = (const float*)d_in[7];
  const float* Wo  = (const float*)d_in[8];
  const float* bo  = (const float*)d_in[9];
  const float* g1h = (const float*)d_in[10];
  const float* b1h = (const float*)d_in[11];
  const float* g1e = (const float*)d_in[12];
  const float* b1e = (const float*)d_in[13];
  const float* W1  = (const float*)d_in[14];
  const float* b1  = (const float*)d_in[15];
  const float* W2  = (const float*)d_in[16];
  const float* b2  = (const float*)d_in[17];
  const float* g2h = (const float*)d_in[18];
  const float* b2h = (const float*)d_in[19];

  float* out = (float*)d_out;
  float* h3  = out;                       // [NN][128]
  float* e2  = out + (size_t)NN*DD;       // [NEDGE][128]

  char* ws = (char*)d_ws;
  size_t off_b = 0;
  auto take = [&](size_t bytes)->char*{
    char* p = ws + off_b; off_b = (off_b + bytes + 255) & ~(size_t)255; return p;
  };
  short* wT     = (short*)take((size_t)147456*2);
  float* ssE    = (float*)take(256*4);
  float* ss1    = (float*)take(256*4);
  float* ss2    = (float*)take(256*4);
  short* Qb     = (short*)take((size_t)NN*DD*2);
  short* Kb     = (short*)take((size_t)NN*DD*2);
  short* Vb     = (short*)take((size_t)NN*DD*2);
  short* hA     = (short*)take((size_t)NN*DD*2);
  float* sArr   = (float*)take((size_t)NEDGE*8*4);
  int*   cnt2   = (int*)take((size_t)2*NN*4);     // counts | cursor
  int*   counts = cnt2;
  int*   cursor = cnt2 + NN;
  int*   offs   = (int*)take((size_t)(NN+1)*4);
  int*   perm   = (int*)take((size_t)NEDGE*4);
  short* h2pre  = (short*)take((size_t)NN*DD*2);
  short* ffn1   = (short*)take((size_t)NN*256*2);
  float* partE  = (float*)take((size_t)8000*256*4);
  float* partH2 = (float*)take((size_t)782*256*4);
  float* partH3 = (float*)take((size_t)782*256*4);

  hipMemsetAsync(cnt2, 0, (size_t)2*NN*4, stream);

  prep_w<<<576,256,0,stream>>>(Wq,Wk,Wv,We,Wo,W1,W2,wT);
  hist_dst<<<2000,256,0,stream>>>(dst, counts);
  scan_counts<<<1,256,0,stream>>>(counts, offs);
  scatter_perm<<<2000,256,0,stream>>>(dst, offs, cursor, perm);
  qkv_gemm<<<782,256,0,stream>>>(h, wT, Qb, Kb, Vb);
  edge_fused<<<8000,256,0,stream>>>(e, wT+49152, Qb, Kb, src, dst,
                                    sArr, partE);
  bn_reduce<<<128,256,0,stream>>>(partE, 8000, 1.f/(float)NEDGE, g1e, b1e, ssE);
  edge_apply<<<8000,256,0,stream>>>(e, wT+49152, ssE, e2);
  node_agg<<<12500,256,0,stream>>>(offs, perm, src, sArr, Vb, hA);
  attn_out<<<782,256,0,stream>>>(hA, wT+65536, bo, h, h2pre, partH2);
  bn_reduce<<<128,256,0,stream>>>(partH2, 782, 1.f/(float)NN, g1h, b1h, ss1);
  ffn1_gemm<<<782,256,0,stream>>>(h2pre, ss1, wT+81920, b1, ffn1);
  ffn2_gemm<<<782,256,0,stream>>>(ffn1, wT+114688, b2, h2pre, ss1, h3, partH3);
  bn_reduce<<<128,256,0,stream>>>(partH3, 782, 1.f/(float)NN, g2h, b2h, ss2);
  bn_apply<<<6250,256,0,stream>>>(h3, (size_t)NN, ss2);
}

// Round 5
// 898.724 us; speedup vs baseline: 1.1217x; 1.1217x over previous
//
#include <hip/hip_runtime.h>
#include <math.h>

#define NN 50000
#define NEDGE 512000
#define DD 128

typedef short bf16x8 __attribute__((ext_vector_type(8)));
typedef float f32x4 __attribute__((ext_vector_type(4)));

__device__ __forceinline__ short f2bf(float f){
  union { float f; unsigned u; } v; v.f = f;
  unsigned u = v.u;
  return (short)((u + 0x7fffu + ((u >> 16) & 1u)) >> 16);
}
__device__ __forceinline__ float bf2f(short s){
  union { unsigned u; float f; } v; v.u = ((unsigned)(unsigned short)s) << 16; return v.f;
}

__device__ __forceinline__ bf16x8 packA(const float* __restrict__ rowp, int kbase){
  float4 x = *(const float4*)(rowp + kbase);
  float4 y = *(const float4*)(rowp + kbase + 4);
  bf16x8 r;
  r[0]=f2bf(x.x); r[1]=f2bf(x.y); r[2]=f2bf(x.z); r[3]=f2bf(x.w);
  r[4]=f2bf(y.x); r[5]=f2bf(y.y); r[6]=f2bf(y.z); r[7]=f2bf(y.w);
  return r;
}

// ---------------- weight prep: fp32 W[K][N] -> bf16 WT[N][K] ----------------
__global__ __launch_bounds__(256) void prep_w(
    const float* __restrict__ Wq, const float* __restrict__ Wk,
    const float* __restrict__ Wv, const float* __restrict__ We,
    const float* __restrict__ Wo, const float* __restrict__ W1,
    const float* __restrict__ W2, short* __restrict__ wdst){
  int id = blockIdx.x*256 + threadIdx.x;
  const float* src; short* dst; int K, NCOL, local;
  if (id < 81920){
    int m = id >> 14; local = id & 16383; K = 128; NCOL = 128;
    src = (m==0)?Wq:(m==1)?Wk:(m==2)?Wv:(m==3)?We:Wo;
    dst = wdst + m*16384;
  } else if (id < 114688){
    local = id - 81920; K = 128; NCOL = 256; src = W1; dst = wdst + 81920;
  } else if (id < 147456){
    local = id - 114688; K = 256; NCOL = 128; src = W2; dst = wdst + 114688;
  } else return;
  int k = local / NCOL, n = local % NCOL;
  dst[n*K + k] = f2bf(src[local]);
}

// ---------------- QKV: Q/K/V = h @ Wq/Wk/Wv, stored bf16 ----------------
__global__ __launch_bounds__(256) void qkv_gemm(
    const float* __restrict__ h, const short* __restrict__ wT,
    short* __restrict__ Qb, short* __restrict__ Kb, short* __restrict__ Vb){
  const short* WqT = wT;
  const short* WkT = wT + 16384;
  const short* WvT = wT + 32768;
  int lane = threadIdx.x & 63, wave = threadIdx.x >> 6;
  int r16 = lane & 15, kg = lane >> 4;
  int rowbase = blockIdx.x*64 + wave*16;
  int arow = rowbase + r16; if (arow > NN-1) arow = NN-1;
  const float* Arow = h + (size_t)arow*DD;
  f32x4 acc[3][8];
  #pragma unroll
  for (int m=0;m<3;m++)
    #pragma unroll
    for (int j=0;j<8;j++) acc[m][j] = (f32x4){0.f,0.f,0.f,0.f};
  #pragma unroll
  for (int kc=0;kc<4;kc++){
    int kb = kc*32 + kg*8;
    bf16x8 a = packA(Arow, kb);
    #pragma unroll
    for (int j=0;j<8;j++){
      bf16x8 bq = *(const bf16x8*)(WqT + (j*16+r16)*DD + kb);
      acc[0][j] = __builtin_amdgcn_mfma_f32_16x16x32_bf16(a, bq, acc[0][j], 0,0,0);
      bf16x8 bk = *(const bf16x8*)(WkT + (j*16+r16)*DD + kb);
      acc[1][j] = __builtin_amdgcn_mfma_f32_16x16x32_bf16(a, bk, acc[1][j], 0,0,0);
      bf16x8 bv = *(const bf16x8*)(WvT + (j*16+r16)*DD + kb);
      acc[2][j] = __builtin_amdgcn_mfma_f32_16x16x32_bf16(a, bv, acc[2][j], 0,0,0);
    }
  }
  int orow0 = rowbase + kg*4;
  #pragma unroll
  for (int j=0;j<8;j++){
    #pragma unroll
    for (int r=0;r<4;r++){
      int row = orow0 + r;
      if (row < NN){
        size_t idx = (size_t)row*DD + j*16 + r16;
        Qb[idx] = f2bf(acc[0][j][r]);
        Kb[idx] = f2bf(acc[1][j][r]);
        Vb[idx] = f2bf(acc[2][j][r]);
      }
    }
  }
}

// ---------------- CSR build ----------------
__global__ __launch_bounds__(256) void hist_dst(
    const int* __restrict__ dst, int* __restrict__ counts){
  int id = blockIdx.x*256 + threadIdx.x;
  if (id < NEDGE) atomicAdd(&counts[dst[id]], 1);
}

__global__ __launch_bounds__(256) void scan_counts(
    const int* __restrict__ counts, int* __restrict__ off){
  __shared__ int ps[256];
  int t = threadIdx.x;
  int base = t*196;
  int sum = 0;
  for (int i=0;i<196;i++){ int idx=base+i; if (idx<NN) sum += counts[idx]; }
  ps[t] = sum; __syncthreads();
  for (int o=1;o<256;o<<=1){
    int v2 = (t>=o) ? ps[t-o] : 0;
    __syncthreads();
    ps[t] += v2;
    __syncthreads();
  }
  int run = ps[t] - sum;   // exclusive prefix of this chunk
  for (int i=0;i<196;i++){
    int idx = base+i;
    if (idx < NN){ off[idx] = run; run += counts[idx]; }
  }
  if (t == 255) off[NN] = run;
}

__global__ __launch_bounds__(256) void scatter_perm(
    const int* __restrict__ dst, const int* __restrict__ off,
    int* __restrict__ cursor, int* __restrict__ perm){
  int id = blockIdx.x*256 + threadIdx.x;
  if (id < NEDGE){
    int d = dst[id];
    int r = atomicAdd(&cursor[d], 1);
    perm[off[d] + r] = id;
  }
}

// -------- edge pass: stage e->LDS(bf16,swz), Eh=e@We (MFMA from LDS),
//   scores->sArrB(bf16), e2pre(bf16)->global via LDS, BN stats in regs. --------
// eL swizzle: 16B granule g=col>>3 stored at (g ^ (row&7)); bijective, kills
// the row-stride bank conflict for ds_read_b128 A-fragments.
__global__ __launch_bounds__(256) void edge_fused(
    const float* __restrict__ e, const short* __restrict__ WeT,
    const short* __restrict__ Qb, const short* __restrict__ Kb,
    const int* __restrict__ src, const int* __restrict__ dst,
    short* __restrict__ e2p, short* __restrict__ sArrB,
    float* __restrict__ part){
  __shared__ short eL[64*128];    // 16KB bf16 of e, later overwritten with e+Eh
  __shared__ short EhL[64*128];   // 16KB bf16 Eh (for scores), head-group swz
  __shared__ float csum[DD], csq[DD];
  __shared__ int srcL[64], dstL[64];
  int tid = threadIdx.x;
  int rowbase = blockIdx.x*64;
  if (tid < DD){ csum[tid] = 0.f; csq[tid] = 0.f; }
  if (tid < 64){ srcL[tid] = src[rowbase+tid]; dstL[tid] = dst[rowbase+tid]; }
  // ---- stage: coalesced fp32 read of e (8KB/wave contiguous) -> bf16 LDS ----
  {
    int row = tid >> 2;
    int c0  = (tid & 3) * 32;
    const float* rp = e + (size_t)(rowbase+row)*DD + c0;
    #pragma unroll
    for (int g=0; g<4; ++g){
      float4 x = *(const float4*)(rp + g*8);
      float4 y = *(const float4*)(rp + g*8 + 4);
      bf16x8 v;
      v[0]=f2bf(x.x); v[1]=f2bf(x.y); v[2]=f2bf(x.z); v[3]=f2bf(x.w);
      v[4]=f2bf(y.x); v[5]=f2bf(y.y); v[6]=f2bf(y.z); v[7]=f2bf(y.w);
      int col8 = (c0 >> 3) + g;
      *(bf16x8*)&eL[row*DD + (((col8 ^ (row&7)))<<3)] = v;
    }
  }
  __syncthreads();
  int lane = tid & 63, wave = tid >> 6;
  int c = lane & 15, kg = lane >> 4;
  // ---- MFMA: A from LDS (own 16 rows), B = WeT from global (L2) ----
  f32x4 acc[8];
  #pragma unroll
  for (int j=0;j<8;j++) acc[j] = (f32x4){0.f,0.f,0.f,0.f};
  int arow = wave*16 + c;
  #pragma unroll
  for (int kc=0;kc<4;kc++){
    int col8 = kc*4 + kg;
    bf16x8 a = *(const bf16x8*)&eL[arow*DD + ((col8 ^ (arow&7))<<3)];
    int kb = kc*32 + kg*8;
    #pragma unroll
    for (int j=0;j<8;j++){
      bf16x8 b = *(const bf16x8*)(WeT + (j*16+c)*DD + kb);
      acc[j] = __builtin_amdgcn_mfma_f32_16x16x32_bf16(a, b, acc[j], 0,0,0);
    }
  }
  // ---- stats + writeback: EhL <- Eh;  eL <- e+Eh (both bf16) ----
  float ssum[8], ssq[8];
  #pragma unroll
  for (int j=0;j<8;j++){ ssum[j]=0.f; ssq[j]=0.f; }
  #pragma unroll
  for (int r=0;r<4;r++){
    int le = wave*16 + kg*4 + r;
    int sw = le & 7;
    int rowoff = le*DD;
    #pragma unroll
    for (int j=0;j<8;j++){
      float ehv = acc[j][r];
      EhL[rowoff + ((j^sw)*16) + c] = f2bf(ehv);
      int col = j*16 + c;
      int sidx = rowoff + (((col>>3) ^ sw)<<3) + (col & 7);
      float v = bf2f(eL[sidx]) + ehv;
      eL[sidx] = f2bf(v);
      ssum[j] += v; ssq[j] += v*v;
    }
  }
  #pragma unroll
  for (int j=0;j<8;j++){
    ssum[j] += __shfl_xor(ssum[j],16); ssum[j] += __shfl_xor(ssum[j],32);
    ssq[j]  += __shfl_xor(ssq[j],16);  ssq[j]  += __shfl_xor(ssq[j],32);
  }
  if (kg == 0){
    #pragma unroll
    for (int j=0;j<8;j++){
      atomicAdd(&csum[j*16+c], ssum[j]);
      atomicAdd(&csq[j*16+c],  ssq[j]);
    }
  }
  __syncthreads();
  // ---- copy-out e2pre bf16: 1KB/wave contiguous stores ----
  #pragma unroll
  for (int it=0; it<4; ++it){
    int gi = it*256 + tid;
    int row = gi >> 4;
    int col8 = gi & 15;
    bf16x8 v = *(const bf16x8*)&eL[row*DD + ((col8 ^ (row&7))<<3)];
    *(bf16x8*)(e2p + (size_t)(rowbase+row)*DD + col8*8) = v;
  }
  // ---- scores: one lane per (edge,head) ----
  #pragma unroll
  for (int it=0; it<2; ++it){
    int le = it*32 + (tid >> 3);
    int hd = tid & 7;
    int sj = srcL[le], dj = dstL[le];
    const short* kp = Kb + (size_t)sj*DD + hd*16;
    const short* qp = Qb + (size_t)dj*DD + hd*16;
    bf16x8 k0 = *(const bf16x8*)kp;
    bf16x8 k1 = *(const bf16x8*)(kp+8);
    bf16x8 q0 = *(const bf16x8*)qp;
    bf16x8 q1 = *(const bf16x8*)(qp+8);
    const short* ehp = &EhL[le*DD + ((hd^(le&7))*16)];
    bf16x8 e0 = *(const bf16x8*)ehp;
    bf16x8 e1 = *(const bf16x8*)(ehp+8);
    float p = 0.f;
    #pragma unroll
    for (int i=0;i<8;i++) p += bf2f(k0[i])*bf2f(q0[i])*bf2f(e0[i]);
    #pragma unroll
    for (int i=0;i<8;i++) p += bf2f(k1[i])*bf2f(q1[i])*bf2f(e1[i]);
    p *= 0.25f;
    float s = __expf(fminf(fmaxf(p,-5.f),5.f));
    sArrB[(size_t)(rowbase+le)*8 + hd] = f2bf(s);
  }
  if (tid < DD){
    part[(size_t)blockIdx.x*256 + tid]      = csum[tid];
    part[(size_t)blockIdx.x*256 + DD + tid] = csq[tid];
  }
}

// ---- pure stream: e2 = e2pre(bf16)*scale + shift -> fp32 d_out ----
__global__ __launch_bounds__(256) void bn_apply_e(
    const short* __restrict__ e2p, const float* __restrict__ ssE,
    float* __restrict__ e2){
  size_t gi0 = (size_t)blockIdx.x*256 + threadIdx.x;
  int col0 = (int)(gi0 & 15) * 8;
  float scr[8], shr[8];
  #pragma unroll
  for (int i=0;i<8;i++){ scr[i]=ssE[col0+i]; shr[i]=ssE[DD+col0+i]; }
  size_t stride = (size_t)gridDim.x*256;
  size_t total = (size_t)NEDGE*16;
  for (size_t gi = gi0; gi < total; gi += stride){
    bf16x8 v = *(const bf16x8*)(e2p + gi*8);
    float4 o0, o1;
    o0.x = bf2f(v[0])*scr[0]+shr[0];
    o0.y = bf2f(v[1])*scr[1]+shr[1];
    o0.z = bf2f(v[2])*scr[2]+shr[2];
    o0.w = bf2f(v[3])*scr[3]+shr[3];
    o1.x = bf2f(v[4])*scr[4]+shr[4];
    o1.y = bf2f(v[5])*scr[5]+shr[5];
    o1.z = bf2f(v[6])*scr[6]+shr[6];
    o1.w = bf2f(v[7])*scr[7]+shr[7];
    *(float4*)(e2 + gi*8)     = o0;
    *(float4*)(e2 + gi*8 + 4) = o1;
  }
}

// ---------------- node aggregation: one wave per dst node, no atomics ----------------
__global__ __launch_bounds__(256) void node_agg(
    const int* __restrict__ off, const int* __restrict__ perm,
    const int* __restrict__ src, const short* __restrict__ sArrB,
    const short* __restrict__ Vb, short* __restrict__ hA){
  int wave = threadIdx.x >> 6, lane = threadIdx.x & 63;
  int node = blockIdx.x*4 + wave;
  if (node >= NN) return;
  int beg = off[node], end = off[node+1];
  int col2 = lane*2;
  int hd = lane >> 3;
  float w0 = 0.f, w1 = 0.f, zh = 0.f;
  for (int ed = beg; ed < end; ++ed){
    int pe = perm[ed];
    int sj = src[pe];
    float s = bf2f(sArrB[(size_t)pe*8 + hd]);
    unsigned vv = *(const unsigned*)(Vb + (size_t)sj*DD + col2);
    w0 += bf2f((short)(vv & 0xffff)) * s;
    w1 += bf2f((short)(vv >> 16)) * s;
    zh += s;
  }
  float inv = 1.f/(zh + 1e-6f);
  unsigned outv = (((unsigned)(unsigned short)f2bf(w1*inv)) << 16)
                |  ((unsigned)(unsigned short)f2bf(w0*inv));
  *(unsigned*)(hA + (size_t)node*DD + col2) = outv;
}

// ---------------- h2pre(bf16) = hA @ Wo + bo + h, BN partials ----------------
__global__ __launch_bounds__(256) void attn_out(
    const short* __restrict__ hA,
    const short* __restrict__ WoT, const float* __restrict__ bo,
    const float* __restrict__ h, short* __restrict__ h2pre,
    float* __restrict__ part){
  __shared__ float csum[DD], csq[DD];
  if (threadIdx.x < DD){ csum[threadIdx.x] = 0.f; csq[threadIdx.x] = 0.f; }
  __syncthreads();
  int lane = threadIdx.x & 63, wave = threadIdx.x >> 6;
  int r16 = lane & 15, kg = lane >> 4;
  int rowbase = blockIdx.x*64 + wave*16;
  int arow = rowbase + r16; if (arow > NN-1) arow = NN-1;
  const short* Arow = hA + (size_t)arow*DD;
  f32x4 acc[8];
  #pragma unroll
  for (int j=0;j<8;j++) acc[j] = (f32x4){0.f,0.f,0.f,0.f};
  #pragma unroll
  for (int kc=0;kc<4;kc++){
    int kb = kc*32 + kg*8;
    bf16x8 a = *(const bf16x8*)(Arow + kb);
    #pragma unroll
    for (int j=0;j<8;j++){
      bf16x8 b = *(const bf16x8*)(WoT + (j*16+r16)*DD + kb);
      acc[j] = __builtin_amdgcn_mfma_f32_16x16x32_bf16(a, b, acc[j], 0,0,0);
    }
  }
  int orow0 = rowbase + kg*4;
  #pragma unroll
  for (int j=0;j<8;j++){
    #pragma unroll
    for (int r=0;r<4;r++){
      int row = orow0 + r;
      if (row < NN){
        int col = j*16 + r16;
        float v = acc[j][r] + bo[col] + h[(size_t)row*DD + col];
        h2pre[(size_t)row*DD + col] = f2bf(v);
        atomicAdd(&csum[col], v);
        atomicAdd(&csq[col], v*v);
      }
    }
  }
  __syncthreads();
  if (threadIdx.x < DD){
    part[(size_t)blockIdx.x*256 + threadIdx.x]      = csum[threadIdx.x];
    part[(size_t)blockIdx.x*256 + DD + threadIdx.x] = csq[threadIdx.x];
  }
}

// ---------------- FFN1: relu(BN1(h2pre) @ W1 + b1) -> bf16 ----------------
__global__ __launch_bounds__(256) void ffn1_gemm(
    const short* __restrict__ h2pre, const float* __restrict__ ss1,
    const short* __restrict__ W1T, const float* __restrict__ b1,
    short* __restrict__ ffn1){
  int lane = threadIdx.x & 63, wave = threadIdx.x >> 6;
  int r16 = lane & 15, kg = lane >> 4;
  int rowbase = blockIdx.x*64 + wave*16;
  int arow = rowbase + r16; if (arow > NN-1) arow = NN-1;
  const short* Arow = h2pre + (size_t)arow*DD;
  f32x4 acc[16];
  #pragma unroll
  for (int j=0;j<16;j++) acc[j] = (f32x4){0.f,0.f,0.f,0.f};
  #pragma unroll
  for (int kc=0;kc<4;kc++){
    int kb = kc*32 + kg*8;
    bf16x8 raw = *(const bf16x8*)(Arow + kb);
    float4 s0 = *(const float4*)(ss1 + kb);
    float4 s1 = *(const float4*)(ss1 + kb + 4);
    float4 t0 = *(const float4*)(ss1 + DD + kb);
    float4 t1 = *(const float4*)(ss1 + DD + kb + 4);
    bf16x8 a;
    a[0]=f2bf(bf2f(raw[0])*s0.x+t0.x); a[1]=f2bf(bf2f(raw[1])*s0.y+t0.y);
    a[2]=f2bf(bf2f(raw[2])*s0.z+t0.z); a[3]=f2bf(bf2f(raw[3])*s0.w+t0.w);
    a[4]=f2bf(bf2f(raw[4])*s1.x+t1.x); a[5]=f2bf(bf2f(raw[5])*s1.y+t1.y);
    a[6]=f2bf(bf2f(raw[6])*s1.z+t1.z); a[7]=f2bf(bf2f(raw[7])*s1.w+t1.w);
    #pragma unroll
    for (int j=0;j<16;j++){
      bf16x8 b = *(const bf16x8*)(W1T + (j*16+r16)*DD + kb);
      acc[j] = __builtin_amdgcn_mfma_f32_16x16x32_bf16(a, b, acc[j], 0,0,0);
    }
  }
  int orow0 = rowbase + kg*4;
  #pragma unroll
  for (int j=0;j<16;j++){
    #pragma unroll
    for (int r=0;r<4;r++){
      int row = orow0 + r;
      if (row < NN){
        int col = j*16 + r16;
        float v = fmaxf(acc[j][r] + b1[col], 0.f);
        ffn1[(size_t)row*256 + col] = f2bf(v);
      }
    }
  }
}

// ---------------- FFN2: h3pre = BN1(h2pre) + ffn1 @ W2 + b2, BN partials ----------------
__global__ __launch_bounds__(256) void ffn2_gemm(
    const short* __restrict__ ffn1, const short* __restrict__ W2T,
    const float* __restrict__ b2, const short* __restrict__ h2pre,
    const float* __restrict__ ss1, float* __restrict__ h3pre,
    float* __restrict__ part){
  __shared__ float csum[DD], csq[DD];
  if (threadIdx.x < DD){ csum[threadIdx.x] = 0.f; csq[threadIdx.x] = 0.f; }
  __syncthreads();
  int lane = threadIdx.x & 63, wave = threadIdx.x >> 6;
  int r16 = lane & 15, kg = lane >> 4;
  int rowbase = blockIdx.x*64 + wave*16;
  int arow = rowbase + r16; if (arow > NN-1) arow = NN-1;
  const short* Arow = ffn1 + (size_t)arow*256;
  f32x4 acc[8];
  #pragma unroll
  for (int j=0;j<8;j++) acc[j] = (f32x4){0.f,0.f,0.f,0.f};
  #pragma unroll
  for (int kc=0;kc<8;kc++){
    int kb = kc*32 + kg*8;
    bf16x8 a = *(const bf16x8*)(Arow + kb);
    #pragma unroll
    for (int j=0;j<8;j++){
      bf16x8 b = *(const bf16x8*)(W2T + (j*16+r16)*256 + kb);
      acc[j] = __builtin_amdgcn_mfma_f32_16x16x32_bf16(a, b, acc[j], 0,0,0);
    }
  }
  int orow0 = rowbase + kg*4;
  #pragma unroll
  for (int j=0;j<8;j++){
    #pragma unroll
    for (int r=0;r<4;r++){
      int row = orow0 + r;
      if (row < NN){
        int col = j*16 + r16;
        float x = bf2f(h2pre[(size_t)row*DD + col]);
        float h2bn = x*ss1[col] + ss1[DD+col];
        float v = h2bn + acc[j][r] + b2[col];
        h3pre[(size_t)row*DD + col] = v;
        atomicAdd(&csum[col], v);
        atomicAdd(&csq[col], v*v);
      }
    }
  }
  __syncthreads();
  if (threadIdx.x < DD){
    part[(size_t)blockIdx.x*256 + threadIdx.x]      = csum[threadIdx.x];
    part[(size_t)blockIdx.x*256 + DD + threadIdx.x] = csq[threadIdx.x];
  }
}

// ---------------- BN stats reduce: partials -> scale/shift ----------------
__global__ __launch_bounds__(256) void bn_reduce(
    const float* __restrict__ part, int nparts, float inv_n,
    const float* __restrict__ g, const float* __restrict__ b,
    float* __restrict__ ss){
  int col = blockIdx.x, t = threadIdx.x;
  float s = 0.f, q = 0.f;
  for (int i=t; i<nparts; i+=256){
    s += part[(size_t)i*256 + col];
    q += part[(size_t)i*256 + DD + col];
  }
  __shared__ float ls[256], lq[256];
  ls[t] = s; lq[t] = q; __syncthreads();
  for (int o2=128; o2>0; o2>>=1){
    if (t < o2){ ls[t] += ls[t+o2]; lq[t] += lq[t+o2]; }
    __syncthreads();
  }
  if (t == 0){
    float mean = ls[0]*inv_n;
    float var  = lq[0]*inv_n - mean*mean;
    float sc = g[col]*rsqrtf(var + 1e-5f);
    ss[col]      = sc;
    ss[DD + col] = b[col] - mean*sc;
  }
}

// ---------------- in-place BN apply (h3 only): x = x*scale + shift ----------------
__global__ __launch_bounds__(256) void bn_apply(
    float* __restrict__ x, size_t rows, const float* __restrict__ ss){
  size_t id = (size_t)blockIdx.x*256 + threadIdx.x;
  size_t total = rows*32;
  if (id >= total) return;
  float4* p = (float4*)x + id;
  int c = (int)(id & 31) * 4;
  float4 v = *p;
  v.x = v.x*ss[c]   + ss[DD+c];
  v.y = v.y*ss[c+1] + ss[DD+c+1];
  v.z = v.z*ss[c+2] + ss[DD+c+2];
  v.w = v.w*ss[c+3] + ss[DD+c+3];
  *p = v;
}

extern "C" void kernel_launch(void* const* d_in, const int* in_sizes, int n_in,
                              void* d_out, int out_size, void* d_ws, size_t ws_size,
                              hipStream_t stream){
  const float* h   = (const float*)d_in[0];
  const float* e   = (const float*)d_in[1];
  const int*   src = (const int*)d_in[2];
  const int*   dst = (const int*)d_in[3];
  const float* Wq  = (const float*)d_in[4];
  const float* Wk  = (const float*)d_in[5];
  const float* Wv  = (const float*)d_in[6];
  const float* We  = (const float*)d_in[7];
  const float* Wo  = (const float*)d_in[8];
  const float* bo  = (const float*)d_in[9];
  const float* g1h = (const float*)d_in[10];
  const float* b1h = (const float*)d_in[11];
  const float* g1e = (const float*)d_in[12];
  const float* b1e = (const float*)d_in[13];
  const float* W1  = (const float*)d_in[14];
  const float* b1  = (const float*)d_in[15];
  const float* W2  = (const float*)d_in[16];
  const float* b2  = (const float*)d_in[17];
  const float* g2h = (const float*)d_in[18];
  const float* b2h = (const float*)d_in[19];

  float* out = (float*)d_out;
  float* h3  = out;                       // [NN][128]
  float* e2  = out + (size_t)NN*DD;       // [NEDGE][128]

  char* ws = (char*)d_ws;
  size_t off_b = 0;
  auto take = [&](size_t bytes)->char*{
    char* p = ws + off_b; off_b = (off_b + bytes + 255) & ~(size_t)255; return p;
  };
  short* wT     = (short*)take((size_t)147456*2);
  float* ssE    = (float*)take(256*4);
  float* ss1    = (float*)take(256*4);
  float* ss2    = (float*)take(256*4);
  short* Qb     = (short*)take((size_t)NN*DD*2);
  short* Kb     = (short*)take((size_t)NN*DD*2);
  short* Vb     = (short*)take((size_t)NN*DD*2);
  short* hA     = (short*)take((size_t)NN*DD*2);
  short* e2p    = (short*)take((size_t)NEDGE*DD*2);
  short* sArrB  = (short*)take((size_t)NEDGE*8*2);
  int*   cnt2   = (int*)take((size_t)2*NN*4);     // counts | cursor
  int*   counts = cnt2;
  int*   cursor = cnt2 + NN;
  int*   offs   = (int*)take((size_t)(NN+1)*4);
  int*   perm   = (int*)take((size_t)NEDGE*4);
  short* h2pre  = (short*)take((size_t)NN*DD*2);
  short* ffn1   = (short*)take((size_t)NN*256*2);
  float* partE  = (float*)take((size_t)8000*256*4);
  float* partH2 = (float*)take((size_t)782*256*4);
  float* partH3 = (float*)take((size_t)782*256*4);

  hipMemsetAsync(cnt2, 0, (size_t)2*NN*4, stream);

  prep_w<<<576,256,0,stream>>>(Wq,Wk,Wv,We,Wo,W1,W2,wT);
  hist_dst<<<2000,256,0,stream>>>(dst, counts);
  scan_counts<<<1,256,0,stream>>>(counts, offs);
  scatter_perm<<<2000,256,0,stream>>>(dst, offs, cursor, perm);
  qkv_gemm<<<782,256,0,stream>>>(h, wT, Qb, Kb, Vb);
  edge_fused<<<8000,256,0,stream>>>(e, wT+49152, Qb, Kb, src, dst,
                                    e2p, sArrB, partE);
  bn_reduce<<<128,256,0,stream>>>(partE, 8000, 1.f/(float)NEDGE, g1e, b1e, ssE);
  bn_apply_e<<<2048,256,0,stream>>>(e2p, ssE, e2);
  node_agg<<<12500,256,0,stream>>>(offs, perm, src, sArrB, Vb, hA);
  attn_out<<<782,256,0,stream>>>(hA, wT+65536, bo, h, h2pre, partH2);
  bn_reduce<<<128,256,0,stream>>>(partH2, 782, 1.f/(float)NN, g1h, b1h, ss1);
  ffn1_gemm<<<782,256,0,stream>>>(h2pre, ss1, wT+81920, b1, ffn1);
  ffn2_gemm<<<782,256,0,stream>>>(ffn1, wT+114688, b2, h2pre, ss1, h3, partH3);
  bn_reduce<<<128,256,0,stream>>>(partH3, 782, 1.f/(float)NN, g2h, b2h, ss2);
  bn_apply<<<6250,256,0,stream>>>(h3, (size_t)NN, ss2);
}

// Round 6
// 855.741 us; speedup vs baseline: 1.1780x; 1.0502x over previous
//
#include <hip/hip_runtime.h>
#include <math.h>

#define NN 50000
#define NEDGE 512000
#define DD 128

typedef short bf16x8 __attribute__((ext_vector_type(8)));
typedef float f32x4 __attribute__((ext_vector_type(4)));

__device__ __forceinline__ short f2bf(float f){
  union { float f; unsigned u; } v; v.f = f;
  unsigned u = v.u;
  return (short)((u + 0x7fffu + ((u >> 16) & 1u)) >> 16);
}
__device__ __forceinline__ float bf2f(short s){
  union { unsigned u; float f; } v; v.u = ((unsigned)(unsigned short)s) << 16; return v.f;
}

__device__ __forceinline__ bf16x8 packA(const float* __restrict__ rowp, int kbase){
  float4 x = *(const float4*)(rowp + kbase);
  float4 y = *(const float4*)(rowp + kbase + 4);
  bf16x8 r;
  r[0]=f2bf(x.x); r[1]=f2bf(x.y); r[2]=f2bf(x.z); r[3]=f2bf(x.w);
  r[4]=f2bf(y.x); r[5]=f2bf(y.y); r[6]=f2bf(y.z); r[7]=f2bf(y.w);
  return r;
}

// ------- kernel A: prep_w (blocks 0..575) + hist_dst (blocks 576..2575) -------
__global__ __launch_bounds__(256) void prep_hist(
    const float* __restrict__ Wq, const float* __restrict__ Wk,
    const float* __restrict__ Wv, const float* __restrict__ We,
    const float* __restrict__ Wo, const float* __restrict__ W1,
    const float* __restrict__ W2, short* __restrict__ wdst,
    const int* __restrict__ dst, int* __restrict__ counts){
  if (blockIdx.x >= 576){
    int id = (blockIdx.x-576)*256 + threadIdx.x;
    if (id < NEDGE) atomicAdd(&counts[dst[id]], 1);
    return;
  }
  int id = blockIdx.x*256 + threadIdx.x;
  const float* src; short* dstp; int K, NCOL, local;
  if (id < 81920){
    int m = id >> 14; local = id & 16383; K = 128; NCOL = 128;
    src = (m==0)?Wq:(m==1)?Wk:(m==2)?Wv:(m==3)?We:Wo;
    dstp = wdst + m*16384;
  } else if (id < 114688){
    local = id - 81920; K = 128; NCOL = 256; src = W1; dstp = wdst + 81920;
  } else if (id < 147456){
    local = id - 114688; K = 256; NCOL = 128; src = W2; dstp = wdst + 114688;
  } else return;
  int k = local / NCOL, n = local % NCOL;
  dstp[n*K + k] = f2bf(src[local]);
}

__global__ __launch_bounds__(256) void scan_counts(
    const int* __restrict__ counts, int* __restrict__ off){
  __shared__ int ps[256];
  int t = threadIdx.x;
  int base = t*196;
  int sum = 0;
  for (int i=0;i<196;i++){ int idx=base+i; if (idx<NN) sum += counts[idx]; }
  ps[t] = sum; __syncthreads();
  for (int o=1;o<256;o<<=1){
    int v2 = (t>=o) ? ps[t-o] : 0;
    __syncthreads();
    ps[t] += v2;
    __syncthreads();
  }
  int run = ps[t] - sum;
  for (int i=0;i<196;i++){
    int idx = base+i;
    if (idx < NN){ off[idx] = run; run += counts[idx]; }
  }
  if (t == 255) off[NN] = run;
}

// ------- kernel B: qkv_gemm (blocks 0..781) + scatter_perm (rest) -------
__global__ __launch_bounds__(256) void qkv_scatter(
    const float* __restrict__ h, const short* __restrict__ wT,
    short* __restrict__ Qb, short* __restrict__ Kb, short* __restrict__ Vb,
    const int* __restrict__ dst, const int* __restrict__ off,
    int* __restrict__ cursor, int* __restrict__ perm){
  if (blockIdx.x >= 782){
    int id = (blockIdx.x-782)*256 + threadIdx.x;
    if (id < NEDGE){
      int d = dst[id];
      int r = atomicAdd(&cursor[d], 1);
      perm[off[d] + r] = id;
    }
    return;
  }
  const short* WqT = wT;
  const short* WkT = wT + 16384;
  const short* WvT = wT + 32768;
  int lane = threadIdx.x & 63, wave = threadIdx.x >> 6;
  int r16 = lane & 15, kg = lane >> 4;
  int rowbase = blockIdx.x*64 + wave*16;
  int arow = rowbase + r16; if (arow > NN-1) arow = NN-1;
  const float* Arow = h + (size_t)arow*DD;
  f32x4 acc[3][8];
  #pragma unroll
  for (int m=0;m<3;m++)
    #pragma unroll
    for (int j=0;j<8;j++) acc[m][j] = (f32x4){0.f,0.f,0.f,0.f};
  #pragma unroll
  for (int kc=0;kc<4;kc++){
    int kb = kc*32 + kg*8;
    bf16x8 a = packA(Arow, kb);
    #pragma unroll
    for (int j=0;j<8;j++){
      bf16x8 bq = *(const bf16x8*)(WqT + (j*16+r16)*DD + kb);
      acc[0][j] = __builtin_amdgcn_mfma_f32_16x16x32_bf16(a, bq, acc[0][j], 0,0,0);
      bf16x8 bk = *(const bf16x8*)(WkT + (j*16+r16)*DD + kb);
      acc[1][j] = __builtin_amdgcn_mfma_f32_16x16x32_bf16(a, bk, acc[1][j], 0,0,0);
      bf16x8 bv = *(const bf16x8*)(WvT + (j*16+r16)*DD + kb);
      acc[2][j] = __builtin_amdgcn_mfma_f32_16x16x32_bf16(a, bv, acc[2][j], 0,0,0);
    }
  }
  int orow0 = rowbase + kg*4;
  #pragma unroll
  for (int j=0;j<8;j++){
    #pragma unroll
    for (int r=0;r<4;r++){
      int row = orow0 + r;
      if (row < NN){
        size_t idx = (size_t)row*DD + j*16 + r16;
        Qb[idx] = f2bf(acc[0][j][r]);
        Kb[idx] = f2bf(acc[1][j][r]);
        Vb[idx] = f2bf(acc[2][j][r]);
      }
    }
  }
}

// -------- edge pass: stage e->LDS(bf16,swz, wave-private rows), Eh=e@We,
//   in-register scores (shfl reduce) -> sArrB, eL overwritten with e+Eh,
//   coalesced copy-out to e2p(bf16), BN stats in regs -> LDS -> part. --------
__global__ __launch_bounds__(256) void edge_fused(
    const float* __restrict__ e, const short* __restrict__ WeT,
    const short* __restrict__ Qb, const short* __restrict__ Kb,
    const int* __restrict__ src, const int* __restrict__ dst,
    short* __restrict__ e2p, short* __restrict__ sArrB,
    float* __restrict__ part){
  __shared__ short eL[64*128];    // 16KB; rows [w*16,w*16+16) private to wave w
  __shared__ float csum[DD], csq[DD];
  int tid = threadIdx.x;
  int rowbase = blockIdx.x*64;
  if (tid < DD){ csum[tid] = 0.f; csq[tid] = 0.f; }
  // ---- stage: coalesced fp32 read of e -> bf16 LDS (swizzled granules) ----
  {
    int row = tid >> 2;
    int c0  = (tid & 3) * 32;
    const float* rp = e + (size_t)(rowbase+row)*DD + c0;
    #pragma unroll
    for (int g=0; g<4; ++g){
      float4 x = *(const float4*)(rp + g*8);
      float4 y = *(const float4*)(rp + g*8 + 4);
      bf16x8 v;
      v[0]=f2bf(x.x); v[1]=f2bf(x.y); v[2]=f2bf(x.z); v[3]=f2bf(x.w);
      v[4]=f2bf(y.x); v[5]=f2bf(y.y); v[6]=f2bf(y.z); v[7]=f2bf(y.w);
      int col8 = (c0 >> 3) + g;
      *(bf16x8*)&eL[row*DD + ((col8 ^ (row&7))<<3)] = v;
    }
  }
  __syncthreads();
  int lane = tid & 63, wave = tid >> 6;
  int c = lane & 15, kg = lane >> 4;
  // ---- MFMA: A from LDS (own wave's 16 rows), B = WeT (L2-resident) ----
  f32x4 acc[8];
  #pragma unroll
  for (int j=0;j<8;j++) acc[j] = (f32x4){0.f,0.f,0.f,0.f};
  int arow = wave*16 + c;
  #pragma unroll
  for (int kc=0;kc<4;kc++){
    int col8 = kc*4 + kg;
    bf16x8 a = *(const bf16x8*)&eL[arow*DD + ((col8 ^ (arow&7))<<3)];
    int kb = kc*32 + kg*8;
    #pragma unroll
    for (int j=0;j<8;j++){
      bf16x8 b = *(const bf16x8*)(WeT + (j*16+c)*DD + kb);
      acc[j] = __builtin_amdgcn_mfma_f32_16x16x32_bf16(a, b, acc[j], 0,0,0);
    }
  }
  // ---- stats + in-place v = e + Eh (wave-private rows, no barrier) ----
  float ssum[8], ssq[8];
  #pragma unroll
  for (int j=0;j<8;j++){ ssum[j]=0.f; ssq[j]=0.f; }
  #pragma unroll
  for (int r=0;r<4;r++){
    int le = wave*16 + kg*4 + r;
    int sw = le & 7;
    int rowoff = le*DD;
    #pragma unroll
    for (int j=0;j<8;j++){
      int col = j*16 + c;
      int sidx = rowoff + (((col>>3) ^ sw)<<3) + (col & 7);
      float v = bf2f(eL[sidx]) + acc[j][r];
      eL[sidx] = f2bf(v);
      ssum[j] += v; ssq[j] += v*v;
    }
  }
  #pragma unroll
  for (int j=0;j<8;j++){
    ssum[j] += __shfl_xor(ssum[j],16); ssum[j] += __shfl_xor(ssum[j],32);
    ssq[j]  += __shfl_xor(ssq[j],16);  ssq[j]  += __shfl_xor(ssq[j],32);
  }
  if (kg == 0){
    #pragma unroll
    for (int j=0;j<8;j++){
      atomicAdd(&csum[j*16+c], ssum[j]);
      atomicAdd(&csq[j*16+c],  ssq[j]);
    }
  }
  // ---- scores fully in-register: lanes c=0..15 of group kg hold the 16
  //      columns of head j for edge le; 4-step shfl_xor reduces the dot. ----
  #pragma unroll
  for (int r=0;r<4;r++){
    int le = wave*16 + kg*4 + r;
    int ed = rowbase + le;
    int sj = src[ed], dj = dst[ed];   // uniform within 16-lane group
    const short* kp = Kb + (size_t)sj*DD + c;
    const short* qp = Qb + (size_t)dj*DD + c;
    float sreg = 0.f;
    #pragma unroll
    for (int j=0;j<8;j++){
      float p = bf2f(kp[j*16]) * bf2f(qp[j*16]) * acc[j][r];
      p += __shfl_xor(p,1); p += __shfl_xor(p,2);
      p += __shfl_xor(p,4); p += __shfl_xor(p,8);
      if (c == j) sreg = p;
    }
    if (c < 8){
      float s = __expf(fminf(fmaxf(sreg*0.25f,-5.f),5.f));
      sArrB[(size_t)ed*8 + c] = f2bf(s);
    }
  }
  // ---- copy-out e2pre bf16 (wave-local rows, 16B/lane coalesced) ----
  #pragma unroll
  for (int it=0; it<4; ++it){
    int row = wave*16 + it*4 + (lane>>4);
    int col8 = lane & 15;
    bf16x8 v = *(const bf16x8*)&eL[row*DD + ((col8 ^ (row&7))<<3)];
    *(bf16x8*)(e2p + (size_t)(rowbase+row)*DD + col8*8) = v;
  }
  __syncthreads();
  if (tid < DD){
    part[(size_t)blockIdx.x*256 + tid]      = csum[tid];
    part[(size_t)blockIdx.x*256 + DD + tid] = csq[tid];
  }
}

// ------- merged: node aggregation (blocks 0..12499) + e2 BN stream (rest) -------
__global__ __launch_bounds__(256) void agg_bn(
    const int* __restrict__ off, const int* __restrict__ perm,
    const int* __restrict__ src, const short* __restrict__ sArrB,
    const short* __restrict__ Vb, short* __restrict__ hA,
    const short* __restrict__ e2p, const float* __restrict__ ssE,
    float* __restrict__ e2){
  if (blockIdx.x >= 12500){
    // ---- pure stream: e2 = e2pre(bf16)*scale + shift -> fp32 d_out ----
    size_t gi0 = (size_t)(blockIdx.x-12500)*256 + threadIdx.x;
    int col0 = (int)(gi0 & 15) * 8;
    float scr[8], shr[8];
    #pragma unroll
    for (int i=0;i<8;i++){ scr[i]=ssE[col0+i]; shr[i]=ssE[DD+col0+i]; }
    size_t stride = (size_t)2048*256;
    size_t total = (size_t)NEDGE*16;
    for (size_t gi = gi0; gi < total; gi += stride){
      bf16x8 v = *(const bf16x8*)(e2p + gi*8);
      float4 o0, o1;
      o0.x = bf2f(v[0])*scr[0]+shr[0];
      o0.y = bf2f(v[1])*scr[1]+shr[1];
      o0.z = bf2f(v[2])*scr[2]+shr[2];
      o0.w = bf2f(v[3])*scr[3]+shr[3];
      o1.x = bf2f(v[4])*scr[4]+shr[4];
      o1.y = bf2f(v[5])*scr[5]+shr[5];
      o1.z = bf2f(v[6])*scr[6]+shr[6];
      o1.w = bf2f(v[7])*scr[7]+shr[7];
      *(float4*)(e2 + gi*8)     = o0;
      *(float4*)(e2 + gi*8 + 4) = o1;
    }
    return;
  }
  int wave = threadIdx.x >> 6, lane = threadIdx.x & 63;
  int node = blockIdx.x*4 + wave;
  if (node >= NN) return;
  int beg = off[node], end = off[node+1];
  int col2 = lane*2;
  int hd = lane >> 3;
  float w0 = 0.f, w1 = 0.f, zh = 0.f;
  int ed = beg;
  for (; ed+1 < end; ed += 2){
    int pe0 = perm[ed], pe1 = perm[ed+1];
    int sj0 = src[pe0], sj1 = src[pe1];
    float s0 = bf2f(sArrB[(size_t)pe0*8 + hd]);
    float s1 = bf2f(sArrB[(size_t)pe1*8 + hd]);
    unsigned v0 = *(const unsigned*)(Vb + (size_t)sj0*DD + col2);
    unsigned v1 = *(const unsigned*)(Vb + (size_t)sj1*DD + col2);
    w0 += bf2f((short)(v0 & 0xffff))*s0 + bf2f((short)(v1 & 0xffff))*s1;
    w1 += bf2f((short)(v0 >> 16))*s0   + bf2f((short)(v1 >> 16))*s1;
    zh += s0 + s1;
  }
  if (ed < end){
    int pe = perm[ed];
    int sj = src[pe];
    float s = bf2f(sArrB[(size_t)pe*8 + hd]);
    unsigned vv = *(const unsigned*)(Vb + (size_t)sj*DD + col2);
    w0 += bf2f((short)(vv & 0xffff)) * s;
    w1 += bf2f((short)(vv >> 16)) * s;
    zh += s;
  }
  float inv = 1.f/(zh + 1e-6f);
  unsigned outv = (((unsigned)(unsigned short)f2bf(w1*inv)) << 16)
                |  ((unsigned)(unsigned short)f2bf(w0*inv));
  *(unsigned*)(hA + (size_t)node*DD + col2) = outv;
}

// ---------------- h2pre(bf16) = hA @ Wo + bo + h, BN partials ----------------
__global__ __launch_bounds__(256) void attn_out(
    const short* __restrict__ hA,
    const short* __restrict__ WoT, const float* __restrict__ bo,
    const float* __restrict__ h, short* __restrict__ h2pre,
    float* __restrict__ part){
  __shared__ float csum[DD], csq[DD];
  if (threadIdx.x < DD){ csum[threadIdx.x] = 0.f; csq[threadIdx.x] = 0.f; }
  __syncthreads();
  int lane = threadIdx.x & 63, wave = threadIdx.x >> 6;
  int r16 = lane & 15, kg = lane >> 4;
  int rowbase = blockIdx.x*64 + wave*16;
  int arow = rowbase + r16; if (arow > NN-1) arow = NN-1;
  const short* Arow = hA + (size_t)arow*DD;
  f32x4 acc[8];
  #pragma unroll
  for (int j=0;j<8;j++) acc[j] = (f32x4){0.f,0.f,0.f,0.f};
  #pragma unroll
  for (int kc=0;kc<4;kc++){
    int kb = kc*32 + kg*8;
    bf16x8 a = *(const bf16x8*)(Arow + kb);
    #pragma unroll
    for (int j=0;j<8;j++){
      bf16x8 b = *(const bf16x8*)(WoT + (j*16+r16)*DD + kb);
      acc[j] = __builtin_amdgcn_mfma_f32_16x16x32_bf16(a, b, acc[j], 0,0,0);
    }
  }
  int orow0 = rowbase + kg*4;
  #pragma unroll
  for (int j=0;j<8;j++){
    #pragma unroll
    for (int r=0;r<4;r++){
      int row = orow0 + r;
      if (row < NN){
        int col = j*16 + r16;
        float v = acc[j][r] + bo[col] + h[(size_t)row*DD + col];
        h2pre[(size_t)row*DD + col] = f2bf(v);
        atomicAdd(&csum[col], v);
        atomicAdd(&csq[col], v*v);
      }
    }
  }
  __syncthreads();
  if (threadIdx.x < DD){
    part[(size_t)blockIdx.x*256 + threadIdx.x]      = csum[threadIdx.x];
    part[(size_t)blockIdx.x*256 + DD + threadIdx.x] = csq[threadIdx.x];
  }
}

// ---------------- FFN1: relu(BN1(h2pre) @ W1 + b1) -> bf16 ----------------
__global__ __launch_bounds__(256) void ffn1_gemm(
    const short* __restrict__ h2pre, const float* __restrict__ ss1,
    const short* __restrict__ W1T, const float* __restrict__ b1,
    short* __restrict__ ffn1){
  int lane = threadIdx.x & 63, wave = threadIdx.x >> 6;
  int r16 = lane & 15, kg = lane >> 4;
  int rowbase = blockIdx.x*64 + wave*16;
  int arow = rowbase + r16; if (arow > NN-1) arow = NN-1;
  const short* Arow = h2pre + (size_t)arow*DD;
  f32x4 acc[16];
  #pragma unroll
  for (int j=0;j<16;j++) acc[j] = (f32x4){0.f,0.f,0.f,0.f};
  #pragma unroll
  for (int kc=0;kc<4;kc++){
    int kb = kc*32 + kg*8;
    bf16x8 raw = *(const bf16x8*)(Arow + kb);
    float4 s0 = *(const float4*)(ss1 + kb);
    float4 s1 = *(const float4*)(ss1 + kb + 4);
    float4 t0 = *(const float4*)(ss1 + DD + kb);
    float4 t1 = *(const float4*)(ss1 + DD + kb + 4);
    bf16x8 a;
    a[0]=f2bf(bf2f(raw[0])*s0.x+t0.x); a[1]=f2bf(bf2f(raw[1])*s0.y+t0.y);
    a[2]=f2bf(bf2f(raw[2])*s0.z+t0.z); a[3]=f2bf(bf2f(raw[3])*s0.w+t0.w);
    a[4]=f2bf(bf2f(raw[4])*s1.x+t1.x); a[5]=f2bf(bf2f(raw[5])*s1.y+t1.y);
    a[6]=f2bf(bf2f(raw[6])*s1.z+t1.z); a[7]=f2bf(bf2f(raw[7])*s1.w+t1.w);
    #pragma unroll
    for (int j=0;j<16;j++){
      bf16x8 b = *(const bf16x8*)(W1T + (j*16+r16)*DD + kb);
      acc[j] = __builtin_amdgcn_mfma_f32_16x16x32_bf16(a, b, acc[j], 0,0,0);
    }
  }
  int orow0 = rowbase + kg*4;
  #pragma unroll
  for (int j=0;j<16;j++){
    #pragma unroll
    for (int r=0;r<4;r++){
      int row = orow0 + r;
      if (row < NN){
        int col = j*16 + r16;
        float v = fmaxf(acc[j][r] + b1[col], 0.f);
        ffn1[(size_t)row*256 + col] = f2bf(v);
      }
    }
  }
}

// ---------------- FFN2: h3pre = BN1(h2pre) + ffn1 @ W2 + b2, BN partials ----------------
__global__ __launch_bounds__(256) void ffn2_gemm(
    const short* __restrict__ ffn1, const short* __restrict__ W2T,
    const float* __restrict__ b2, const short* __restrict__ h2pre,
    const float* __restrict__ ss1, float* __restrict__ h3pre,
    float* __restrict__ part){
  __shared__ float csum[DD], csq[DD];
  if (threadIdx.x < DD){ csum[threadIdx.x] = 0.f; csq[threadIdx.x] = 0.f; }
  __syncthreads();
  int lane = threadIdx.x & 63, wave = threadIdx.x >> 6;
  int r16 = lane & 15, kg = lane >> 4;
  int rowbase = blockIdx.x*64 + wave*16;
  int arow = rowbase + r16; if (arow > NN-1) arow = NN-1;
  const short* Arow = ffn1 + (size_t)arow*256;
  f32x4 acc[8];
  #pragma unroll
  for (int j=0;j<8;j++) acc[j] = (f32x4){0.f,0.f,0.f,0.f};
  #pragma unroll
  for (int kc=0;kc<8;kc++){
    int kb = kc*32 + kg*8;
    bf16x8 a = *(const bf16x8*)(Arow + kb);
    #pragma unroll
    for (int j=0;j<8;j++){
      bf16x8 b = *(const bf16x8*)(W2T + (j*16+r16)*256 + kb);
      acc[j] = __builtin_amdgcn_mfma_f32_16x16x32_bf16(a, b, acc[j], 0,0,0);
    }
  }
  int orow0 = rowbase + kg*4;
  #pragma unroll
  for (int j=0;j<8;j++){
    #pragma unroll
    for (int r=0;r<4;r++){
      int row = orow0 + r;
      if (row < NN){
        int col = j*16 + r16;
        float x = bf2f(h2pre[(size_t)row*DD + col]);
        float h2bn = x*ss1[col] + ss1[DD+col];
        float v = h2bn + acc[j][r] + b2[col];
        h3pre[(size_t)row*DD + col] = v;
        atomicAdd(&csum[col], v);
        atomicAdd(&csq[col], v*v);
      }
    }
  }
  __syncthreads();
  if (threadIdx.x < DD){
    part[(size_t)blockIdx.x*256 + threadIdx.x]      = csum[threadIdx.x];
    part[(size_t)blockIdx.x*256 + DD + threadIdx.x] = csq[threadIdx.x];
  }
}

// ---------------- BN stats reduce: partials -> scale/shift ----------------
__global__ __launch_bounds__(256) void bn_reduce(
    const float* __restrict__ part, int nparts, float inv_n,
    const float* __restrict__ g, const float* __restrict__ b,
    float* __restrict__ ss){
  int col = blockIdx.x, t = threadIdx.x;
  float s = 0.f, q = 0.f;
  for (int i=t; i<nparts; i+=256){
    s += part[(size_t)i*256 + col];
    q += part[(size_t)i*256 + DD + col];
  }
  __shared__ float ls[256], lq[256];
  ls[t] = s; lq[t] = q; __syncthreads();
  for (int o2=128; o2>0; o2>>=1){
    if (t < o2){ ls[t] += ls[t+o2]; lq[t] += lq[t+o2]; }
    __syncthreads();
  }
  if (t == 0){
    float mean = ls[0]*inv_n;
    float var  = lq[0]*inv_n - mean*mean;
    float sc = g[col]*rsqrtf(var + 1e-5f);
    ss[col]      = sc;
    ss[DD + col] = b[col] - mean*sc;
  }
}

// ---------------- in-place BN apply (h3 only): x = x*scale + shift ----------------
__global__ __launch_bounds__(256) void bn_apply(
    float* __restrict__ x, size_t rows, const float* __restrict__ ss){
  size_t id = (size_t)blockIdx.x*256 + threadIdx.x;
  size_t total = rows*32;
  if (id >= total) return;
  float4* p = (float4*)x + id;
  int c = (int)(id & 31) * 4;
  float4 v = *p;
  v.x = v.x*ss[c]   + ss[DD+c];
  v.y = v.y*ss[c+1] + ss[DD+c+1];
  v.z = v.z*ss[c+2] + ss[DD+c+2];
  v.w = v.w*ss[c+3] + ss[DD+c+3];
  *p = v;
}

extern "C" void kernel_launch(void* const* d_in, const int* in_sizes, int n_in,
                              void* d_out, int out_size, void* d_ws, size_t ws_size,
                              hipStream_t stream){
  const float* h   = (const float*)d_in[0];
  const float* e   = (const float*)d_in[1];
  const int*   src = (const int*)d_in[2];
  const int*   dst = (const int*)d_in[3];
  const float* Wq  = (const float*)d_in[4];
  const float* Wk  = (const float*)d_in[5];
  const float* Wv  = (const float*)d_in[6];
  const float* We  = (const float*)d_in[7];
  const float* Wo  = (const float*)d_in[8];
  const float* bo  = (const float*)d_in[9];
  const float* g1h = (const float*)d_in[10];
  const float* b1h = (const float*)d_in[11];
  const float* g1e = (const float*)d_in[12];
  const float* b1e = (const float*)d_in[13];
  const float* W1  = (const float*)d_in[14];
  const float* b1  = (const float*)d_in[15];
  const float* W2  = (const float*)d_in[16];
  const float* b2  = (const float*)d_in[17];
  const float* g2h = (const float*)d_in[18];
  const float* b2h = (const float*)d_in[19];

  float* out = (float*)d_out;
  float* h3  = out;                       // [NN][128]
  float* e2  = out + (size_t)NN*DD;       // [NEDGE][128]

  char* ws = (char*)d_ws;
  size_t off_b = 0;
  auto take = [&](size_t bytes)->char*{
    char* p = ws + off_b; off_b = (off_b + bytes + 255) & ~(size_t)255; return p;
  };
  short* wT     = (short*)take((size_t)147456*2);
  float* ssE    = (float*)take(256*4);
  float* ss1    = (float*)take(256*4);
  float* ss2    = (float*)take(256*4);
  short* Qb     = (short*)take((size_t)NN*DD*2);
  short* Kb     = (short*)take((size_t)NN*DD*2);
  short* Vb     = (short*)take((size_t)NN*DD*2);
  short* hA     = (short*)take((size_t)NN*DD*2);
  short* e2p    = (short*)take((size_t)NEDGE*DD*2);
  short* sArrB  = (short*)take((size_t)NEDGE*8*2);
  int*   cnt2   = (int*)take((size_t)2*NN*4);     // counts | cursor
  int*   counts = cnt2;
  int*   cursor = cnt2 + NN;
  int*   offs   = (int*)take((size_t)(NN+1)*4);
  int*   perm   = (int*)take((size_t)NEDGE*4);
  short* h2pre  = (short*)take((size_t)NN*DD*2);
  short* ffn1   = (short*)take((size_t)NN*256*2);
  float* partE  = (float*)take((size_t)8000*256*4);
  float* partH2 = (float*)take((size_t)782*256*4);
  float* partH3 = (float*)take((size_t)782*256*4);

  hipMemsetAsync(cnt2, 0, (size_t)2*NN*4, stream);

  prep_hist<<<2576,256,0,stream>>>(Wq,Wk,Wv,We,Wo,W1,W2,wT, dst, counts);
  scan_counts<<<1,256,0,stream>>>(counts, offs);
  qkv_scatter<<<2782,256,0,stream>>>(h, wT, Qb, Kb, Vb, dst, offs, cursor, perm);
  edge_fused<<<8000,256,0,stream>>>(e, wT+49152, Qb, Kb, src, dst,
                                    e2p, sArrB, partE);
  bn_reduce<<<128,256,0,stream>>>(partE, 8000, 1.f/(float)NEDGE, g1e, b1e, ssE);
  agg_bn<<<14548,256,0,stream>>>(offs, perm, src, sArrB, Vb, hA, e2p, ssE, e2);
  attn_out<<<782,256,0,stream>>>(hA, wT+65536, bo, h, h2pre, partH2);
  bn_reduce<<<128,256,0,stream>>>(partH2, 782, 1.f/(float)NN, g1h, b1h, ss1);
  ffn1_gemm<<<782,256,0,stream>>>(h2pre, ss1, wT+81920, b1, ffn1);
  ffn2_gemm<<<782,256,0,stream>>>(ffn1, wT+114688, b2, h2pre, ss1, h3, partH3);
  bn_reduce<<<128,256,0,stream>>>(partH3, 782, 1.f/(float)NN, g2h, b2h, ss2);
  bn_apply<<<6250,256,0,stream>>>(h3, (size_t)NN, ss2);
}